// Round 5
// baseline (217.570 us; speedup 1.0000x reference)
//
#include <hip/hip_runtime.h>

// B=20000, C=64, D=27
// out0[b,c,i,j] = sum_k T1[b,c,3i+k] * T2[b,9k+j] / sqrt(3)   (i,j in 0..8, k in 0..2)
// out1[b,c,i,j] = sum_k T1[b,c,9i+k] * T2[b,3k+j] / 3         (i,j in 0..2, k in 0..8)
// out2[b,c]     = dot(T1[b,c,:27], T2[b,:27]) / sqrt(27)
//
// Barrier-free design: NO LDS, NO __syncthreads (syncthreads forces a full
// vmcnt(0) drain of outstanding stores every iteration — measured ~27% of
// runtime across R2-R4 where LDS restructures were all neutral). Each thread
// loads exactly the T1 floats it needs; the 3x redundant tile reads are served
// by L1/L2 (tile = 6.9 KB, all readers within the same block, tight temporal
// locality), so HBM fetch stays ~1x. Stores go straight from registers; the
// 144B-lane-stride out0 stores cover each 64B line with 4 consecutive
// same-thread instructions -> L2 write-merge keeps HBM lines full.

constexpr int T1_PER_B   = 1728;   // 64*27
constexpr int OUT0_PER_B = 5184;   // 64*81
constexpr int OUT1_PER_B = 576;    // 64*9
constexpr int OUT2_PER_B = 64;

__global__ __launch_bounds__(256, 6) void atc_kernel(
    const float* __restrict__ T1, const float* __restrict__ T2,
    float* __restrict__ out0, float* __restrict__ out1, float* __restrict__ out2,
    int B)
{
    const int tid = threadIdx.x;
    const float n0 = 0.57735026918962576f;  // 1/sqrt(3)
    const float n1 = 0.33333333333333333f;  // 1/3
    const float n2 = 0.19245008972987526f;  // 1/sqrt(27)

    for (int b = blockIdx.x; b < B; b += gridDim.x) {
        // T2[b]: block-uniform address -> scalar (s_load) path, 27 values
        const float* t2p = T2 + (size_t)b * 27;
        float s2[27];
        #pragma unroll
        for (int d = 0; d < 27; ++d) s2[d] = t2p[d];

        const float* t1p = T1 + (size_t)b * T1_PER_B;

        // ---- out0: threads 0-143 own 4 whole (c,i)-rows r=4t..4t+3 ----
        // reads T1[12t..12t+11] (3 lane-contiguous float4), writes 9 float4.
        if (tid < 144) {
            const float4* a4 = reinterpret_cast<const float4*>(t1p) + 3 * tid;
            const float4 A0 = a4[0], A1 = a4[1], A2 = a4[2];
            float af[12];
            #pragma unroll
            for (int u = 0; u < 4; ++u) {
                af[u]     = (&A0.x)[u] * n0;
                af[4 + u] = (&A1.x)[u] * n0;
                af[8 + u] = (&A2.x)[u] * n0;
            }
            float4* o0p = reinterpret_cast<float4*>(out0 + (size_t)b * OUT0_PER_B) + 9 * tid;
            #pragma unroll
            for (int m = 0; m < 9; ++m) {
                float4 r;
                #pragma unroll
                for (int u = 0; u < 4; ++u) {
                    const int e  = 4 * m + u;   // 0..35, compile-time
                    const int rr = e / 9;
                    const int j  = e - rr * 9;
                    (&r.x)[u] = af[3 * rr]     * s2[j]
                              + af[3 * rr + 1] * s2[9 + j]
                              + af[3 * rr + 2] * s2[18 + j];
                }
                o0p[m] = r;
            }
        }

        // ---- out1: threads 0-191, one (c,i)-row R each ----
        // reads T1[9R..9R+8], writes 3 floats (dwordx3 after merge).
        if (tid < 192) {
            const int R = tid;
            const float* a1p = t1p + 9 * R;
            float a[9];
            #pragma unroll
            for (int k = 0; k < 9; ++k) a[k] = a1p[k];
            float* o1p = out1 + (size_t)b * OUT1_PER_B + 3 * R;
            #pragma unroll
            for (int j = 0; j < 3; ++j) {
                float v = 0.f;
                #pragma unroll
                for (int k = 0; k < 9; ++k) v += a[k] * s2[3 * k + j];
                o1p[j] = v * n1;
            }
        } else {
            // ---- out2: wave 3, one channel c each ----
            const int c = tid - 192;
            const float* a2p = t1p + 27 * c;
            float v = 0.f;
            #pragma unroll
            for (int d = 0; d < 27; ++d) v += a2p[d] * s2[d];
            out2[(size_t)b * OUT2_PER_B + c] = v * n2;
        }
    }
}

extern "C" void kernel_launch(void* const* d_in, const int* in_sizes, int n_in,
                              void* d_out, int out_size, void* d_ws, size_t ws_size,
                              hipStream_t stream) {
    const float* T1 = (const float*)d_in[0];
    const float* T2 = (const float*)d_in[1];
    float* out = (float*)d_out;

    const int B = in_sizes[0] / T1_PER_B;   // 20000

    float* out0 = out;
    float* out1 = out0 + (size_t)B * OUT0_PER_B;
    float* out2 = out1 + (size_t)B * OUT1_PER_B;

    int blocks = 2000;                      // B/2000 = 10 iterations each, even
    if (blocks > B) blocks = B;
    atc_kernel<<<dim3(blocks), dim3(256), 0, stream>>>(T1, T2, out0, out1, out2, B);
}

// Round 8
// 95.387 us; speedup vs baseline: 2.2809x; 2.2809x over previous
//
#include <hip/hip_runtime.h>

// B=20000, C=64, D=27
// out0[b,c,i,j] = sum_k T1[b,c,3i+k] * T2[b,9k+j] / sqrt(3)   (i,j in 0..8)
// out1[b,c,i,j] = sum_k T1[b,c,9i+k] * T2[b,3k+j] / 3         (i,j in 0..2)
// out2[b,c]     = dot(T1[b,c,:27], T2[b,:27]) / sqrt(27)
//
// Single-barrier double-buffered pipeline. Per iteration q=it&1:
//   readback(b-1) reads sO0[q^1]/sO1[q^1]; compute(b) sT1d[q]->sO0[q]/sO1[q];
//   stage(b+1) regs->sT1d[q^1]; prefetch(b+2)->regs; ONE __syncthreads.
// All same-iteration accesses touch opposite parities -> race-free.
// R7 bug fixed here: compute must index de-interleaved fragments as
// a_k[rr] (a0_/a1_/a2_), NOT the linear-layout af[3rr+k] (that was R5's
// formula for a linear tile; mixing them computed sum_k T1[12t+3k+rr]).

constexpr int T1_PER_B    = 1728;   // 432 float4
constexpr int OUT0_PER_B  = 5184;   // 1296 float4
constexpr int OUT1_PER_B  = 576;    // 144 float4
constexpr int OUT2_PER_B  = 64;
// sO0 slot stride 145 (odd): write side lane-consecutive (conflict-free),
// readback bank-group (t+m)%8 uniform. 144 would be 9-way conflicted.
constexpr int SLOT_STRIDE = 145;
constexpr int SO0_F4      = 144 + SLOT_STRIDE * 8;  // 1304 float4

// native 16B vector: __builtin_nontemporal_store requires a non-class type
typedef float vf4 __attribute__((ext_vector_type(4)));

__global__ __launch_bounds__(512, 4) void atc_kernel(
    const float* __restrict__ T1, const float* __restrict__ T2,
    float* __restrict__ out0, float* __restrict__ out1, float* __restrict__ out2,
    int B)
{
    // sT1d[q][w][j] = T1[b, 3j+w] (mod-3 de-interleave: all compute reads are
    // lane-consecutive b128 or stride-3/9 runs, <=2 lanes/bank).
    __shared__ __align__(16) float sT1d[2][3][576];     // 13824 B
    __shared__ __align__(16) float sO0[2][SO0_F4 * 4];  // 41728 B
    __shared__ __align__(16) float sO1[2][OUT1_PER_B];  //  4608 B
    // total 60160 B -> 2 blocks/CU (512 thr) = 16 waves/CU

    const int tid = threadIdx.x;
    const int GS  = gridDim.x;
    const float n0 = 0.57735026918962576f;  // 1/sqrt(3)
    const float n1 = 0.33333333333333333f;  // 1/3
    const float n2 = 0.19245008972987526f;  // 1/sqrt(27)

    int b = blockIdx.x;
    if (b >= B) return;

    vf4   p = {0.f, 0.f, 0.f, 0.f};  // T1 prefetch register (threads 0..431)
    float s2c[27], s2n[27];          // T2 current / next

    // ---- prologue: stage T1[b] into buffer 0; prefetch b+GS ----
    {
        if (tid < 432) p = reinterpret_cast<const vf4*>(T1 + (size_t)b * T1_PER_B)[tid];
        const float* t2 = T2 + (size_t)b * 27;
        #pragma unroll
        for (int d = 0; d < 27; ++d) s2c[d] = t2[d];
        if (tid < 432) {
            const int g = tid, gd3 = g / 3, gm3 = g - gd3 * 3;
            #pragma unroll
            for (int u = 0; u < 4; ++u) {
                const int t = gm3 + u, ge = (t >= 3) ? 1 : 0;
                sT1d[0][t - 3 * ge][g + gd3 + ge] = p[u];
            }
        }
        if (b + GS < B) {
            if (tid < 432)
                p = reinterpret_cast<const vf4*>(T1 + (size_t)(b + GS) * T1_PER_B)[tid];
            const float* t2n = T2 + (size_t)(b + GS) * 27;
            #pragma unroll
            for (int d = 0; d < 27; ++d) s2n[d] = t2n[d];
        }
        __syncthreads();
    }

    int it = 0, bprev = -1;
    for (; b < B; b += GS, ++it) {
        const int q = it & 1;

        // ---- 1. readback b_prev (issue stores first: stream all iteration) ----
        if (bprev >= 0) {
            const int pq = q ^ 1;
            const vf4* s0v = reinterpret_cast<const vf4*>(&sO0[pq][0]);
            vf4* o0 = reinterpret_cast<vf4*>(out0 + (size_t)bprev * OUT0_PER_B);
            #pragma unroll
            for (int qq = 0; qq < 2; ++qq) {
                const int F = qq * 512 + tid;
                const int t = F / 9, m = F - 9 * t;
                __builtin_nontemporal_store(s0v[t + SLOT_STRIDE * m], &o0[F]);
            }
            if (tid < 272) {
                const int F = 1024 + tid;
                const int t = F / 9, m = F - 9 * t;
                __builtin_nontemporal_store(s0v[t + SLOT_STRIDE * m], &o0[F]);
            } else if (tid < 416) {
                const int R4 = tid - 272;  // out1 float4 index 0..143
                vf4* o1 = reinterpret_cast<vf4*>(out1 + (size_t)bprev * OUT1_PER_B);
                __builtin_nontemporal_store(
                    reinterpret_cast<const vf4*>(&sO1[pq][0])[R4], &o1[R4]);
            }
        }

        // ---- 2. compute b: sT1d[q] -> sO0[q]/sO1[q]; out2 direct ----
        const float (*sq)[576] = sT1d[q];
        if (tid < 144) {
            // A_k[u] = sT1d[k][4t+u] = T1[12t+3u+k]  -> fragment a_k[rr]
            const vf4 A0 = reinterpret_cast<const vf4*>(&sq[0][0])[tid];
            const vf4 A1 = reinterpret_cast<const vf4*>(&sq[1][0])[tid];
            const vf4 A2 = reinterpret_cast<const vf4*>(&sq[2][0])[tid];
            float a0_[4], a1_[4], a2_[4];
            #pragma unroll
            for (int u = 0; u < 4; ++u) {
                a0_[u] = A0[u] * n0;   // T1[12t+3u+0] * n0  (k=0, rr=u)
                a1_[u] = A1[u] * n0;   // k=1
                a2_[u] = A2[u] * n0;   // k=2
            }
            vf4* so0 = reinterpret_cast<vf4*>(&sO0[q][0]);
            #pragma unroll
            for (int m = 0; m < 9; ++m) {
                vf4 r;
                #pragma unroll
                for (int u = 0; u < 4; ++u) {
                    const int e  = 4 * m + u;   // compile-time 0..35
                    const int rr = e / 9;
                    const int j  = e - rr * 9;
                    r[u] = a0_[rr] * s2c[j] + a1_[rr] * s2c[9 + j]
                         + a2_[rr] * s2c[18 + j];
                }
                so0[tid + SLOT_STRIDE * m] = r;  // lane-consecutive, conflict-free
            }
        } else if (tid < 336) {
            const int R = tid - 144;             // out1 row, 0..191
            float av[3][3];
            #pragma unroll
            for (int w = 0; w < 3; ++w)
                #pragma unroll
                for (int pp = 0; pp < 3; ++pp)
                    av[w][pp] = sq[w][3 * R + pp];   // = T1[9R+3pp+w]
            #pragma unroll
            for (int j = 0; j < 3; ++j) {
                float v = 0.f;
                #pragma unroll
                for (int k = 0; k < 9; ++k)          // k = 3pp+w
                    v += av[k % 3][k / 3] * s2c[3 * k + j];
                sO1[q][3 * R + j] = v * n1;
            }
        } else if (tid < 400) {
            const int c = tid - 336;                 // out2 channel
            float v = 0.f;
            #pragma unroll
            for (int w = 0; w < 3; ++w)
                #pragma unroll
                for (int pp = 0; pp < 9; ++pp)       // d = 3pp+w
                    v += sq[w][9 * c + pp] * s2c[3 * pp + w];
            __builtin_nontemporal_store(v * n2, out2 + (size_t)b * OUT2_PER_B + c);
        }

        // ---- 3. stage b+GS from prefetch regs -> sT1d[q^1] ----
        if (b + GS < B) {
            if (tid < 432) {
                const int g = tid, gd3 = g / 3, gm3 = g - gd3 * 3;
                #pragma unroll
                for (int u = 0; u < 4; ++u) {
                    const int t = gm3 + u, ge = (t >= 3) ? 1 : 0;
                    sT1d[q ^ 1][t - 3 * ge][g + gd3 + ge] = p[u];
                }
            }
            // ---- 4. rotate T2; prefetch b+2GS ----
            #pragma unroll
            for (int d = 0; d < 27; ++d) s2c[d] = s2n[d];
            if (b + 2 * GS < B) {
                if (tid < 432)
                    p = reinterpret_cast<const vf4*>(T1 + (size_t)(b + 2 * GS) * T1_PER_B)[tid];
                const float* t2n = T2 + (size_t)(b + 2 * GS) * 27;
                #pragma unroll
                for (int d = 0; d < 27; ++d) s2n[d] = t2n[d];
            }
        }

        bprev = b;
        __syncthreads();  // the only barrier
    }

    // ---- epilogue: readback last b ----
    {
        const int pq = (it - 1) & 1;
        const vf4* s0v = reinterpret_cast<const vf4*>(&sO0[pq][0]);
        vf4* o0 = reinterpret_cast<vf4*>(out0 + (size_t)bprev * OUT0_PER_B);
        #pragma unroll
        for (int qq = 0; qq < 2; ++qq) {
            const int F = qq * 512 + tid;
            const int t = F / 9, m = F - 9 * t;
            __builtin_nontemporal_store(s0v[t + SLOT_STRIDE * m], &o0[F]);
        }
        if (tid < 272) {
            const int F = 1024 + tid;
            const int t = F / 9, m = F - 9 * t;
            __builtin_nontemporal_store(s0v[t + SLOT_STRIDE * m], &o0[F]);
        } else if (tid < 416) {
            const int R4 = tid - 272;
            vf4* o1 = reinterpret_cast<vf4*>(out1 + (size_t)bprev * OUT1_PER_B);
            __builtin_nontemporal_store(
                reinterpret_cast<const vf4*>(&sO1[pq][0])[R4], &o1[R4]);
        }
    }
}

extern "C" void kernel_launch(void* const* d_in, const int* in_sizes, int n_in,
                              void* d_out, int out_size, void* d_ws, size_t ws_size,
                              hipStream_t stream) {
    const float* T1 = (const float*)d_in[0];
    const float* T2 = (const float*)d_in[1];
    float* out = (float*)d_out;

    const int B = in_sizes[0] / T1_PER_B;   // 20000

    float* out0 = out;
    float* out1 = out0 + (size_t)B * OUT0_PER_B;
    float* out2 = out1 + (size_t)B * OUT1_PER_B;

    int blocks = 512;                       // 2 blocks/CU x 256 CU, single wave
    if (blocks > B) blocks = B;
    atc_kernel<<<dim3(blocks), dim3(512), 0, stream>>>(T1, T2, out0, out1, out2, B);
}